// Round 6
// baseline (261.130 us; speedup 1.0000x reference)
//
#include <hip/hip_runtime.h>
#include <math.h>

#define HDIM 256
#define BSZ 8
#define FNUM 256
#define SEGS (FNUM * BSZ)   /* 2048 */
#define TWOH 512
#define NBLK 256            /* blocks in hist/scatter phases */

typedef float f32x4 __attribute__((ext_vector_type(4)));

// Phase 1: per-block LDS histogram + cache seg ids as u16.
__global__ __launch_bounds__(256) void hist_k(const int* __restrict__ batch,
                                              const int* __restrict__ fid,
                                              unsigned short* __restrict__ seg16,
                                              int* __restrict__ hist_t,
                                              int N, int chunk) {
    __shared__ int h[SEGS];
    int p = blockIdx.x, t = threadIdx.x;
    for (int s = t; s < SEGS; s += 256) h[s] = 0;
    __syncthreads();
    int beg = p * chunk;
    int end = beg + chunk; if (end > N) end = N;
    if (beg < end) {
        int nv = (end - beg) >> 2;
        const int4* b4 = (const int4*)(batch + beg);
        const int4* f4 = (const int4*)(fid + beg);
        ushort4* s4 = (ushort4*)(seg16 + beg);
        for (int j = t; j < nv; j += 256) {
            int4 bb = b4[j];
            int4 ff = f4[j];
            int s0 = ff.x * BSZ + bb.x;
            int s1 = ff.y * BSZ + bb.y;
            int s2 = ff.z * BSZ + bb.z;
            int s3 = ff.w * BSZ + bb.w;
            s4[j] = make_ushort4((unsigned short)s0, (unsigned short)s1,
                                 (unsigned short)s2, (unsigned short)s3);
            atomicAdd(&h[s0], 1);
            atomicAdd(&h[s1], 1);
            atomicAdd(&h[s2], 1);
            atomicAdd(&h[s3], 1);
        }
        for (int i = beg + (nv << 2) + t; i < end; i += 256) {
            int s = fid[i] * BSZ + batch[i];
            seg16[i] = (unsigned short)s;
            atomicAdd(&h[s], 1);
        }
    }
    __syncthreads();
    for (int s = t; s < SEGS; s += 256)
        hist_t[(size_t)s * NBLK + p] = h[s];
}

// Phase 2a: one WAVE per segment; lane l owns 4 contiguous block-counts (int4).
__global__ __launch_bounds__(256) void segscan_k(int* __restrict__ hist_t,
                                                 int* __restrict__ cnt) {
    int wid = (int)((blockIdx.x * 256 + threadIdx.x) >> 6);  // segment id
    int lane = threadIdx.x & 63;
    if (wid >= SEGS) return;
    int4* row = (int4*)(hist_t + (size_t)wid * NBLK) + lane;
    int4 a = *row;
    int lsum = a.x + a.y + a.z + a.w;
    int inc = lsum;
#pragma unroll
    for (int off = 1; off < 64; off <<= 1) {
        int v = __shfl_up(inc, off, 64);
        if (lane >= off) inc += v;
    }
    int r = inc - lsum;  // exclusive base for this lane
    int4 oa;
    oa.x = r; r += a.x; oa.y = r; r += a.y; oa.z = r; r += a.z; oa.w = r; r += a.w;
    *row = oa;
    if (lane == 63) cnt[wid] = inc;
}

// Phase 2b: exclusive scan of 2048 totals -> segment starts. One block.
__global__ void scan_k(const int* __restrict__ cnt, int* __restrict__ starts) {
    __shared__ int part[256];
    int t = threadIdx.x;
    int local[8];
    int s = 0;
#pragma unroll
    for (int j = 0; j < 8; ++j) { local[j] = cnt[t * 8 + j]; s += local[j]; }
    part[t] = s;
    __syncthreads();
    for (int off = 1; off < 256; off <<= 1) {
        int v = (t >= off) ? part[t - off] : 0;
        __syncthreads();
        part[t] += v;
        __syncthreads();
    }
    int run = (t == 0) ? 0 : part[t - 1];
#pragma unroll
    for (int j = 0; j < 8; ++j) {
        starts[t * 8 + j] = run;
        run += local[j];
    }
}

// Phase 3: deterministic-base scatter; LDS atomics only.
__global__ __launch_bounds__(256) void scatter_k(const unsigned short* __restrict__ seg16,
                                                 const int* __restrict__ hist_t,
                                                 const int* __restrict__ starts,
                                                 int* __restrict__ sorted,
                                                 int N, int chunk) {
    __shared__ int off[SEGS];
    int p = blockIdx.x, t = threadIdx.x;
    for (int s = t; s < SEGS; s += 256)
        off[s] = starts[s] + hist_t[(size_t)s * NBLK + p];
    __syncthreads();
    int beg = p * chunk;
    int end = beg + chunk; if (end > N) end = N;
    if (beg < end) {
        int nv = (end - beg) >> 2;
        const ushort4* s4 = (const ushort4*)(seg16 + beg);
        for (int j = t; j < nv; j += 256) {
            ushort4 ss = s4[j];
            int i0 = beg + 4 * j;
            sorted[atomicAdd(&off[ss.x], 1)] = i0;
            sorted[atomicAdd(&off[ss.y], 1)] = i0 + 1;
            sorted[atomicAdd(&off[ss.z], 1)] = i0 + 2;
            sorted[atomicAdd(&off[ss.w], 1)] = i0 + 3;
        }
        for (int i = beg + (nv << 2) + t; i < end; i += 256)
            sorted[atomicAdd(&off[seg16[i]], 1)] = i;
    }
}

// one block per segment: 256 threads = 64 lanes (float4 over 256 dims) x 4 row groups.
// 8-deep row unroll: 8 outstanding 1 KB wave-gathers; 512-row index chunks.
__global__ __launch_bounds__(256, 8) void segreduce_k(const f32x4* __restrict__ x4,
                                                      const int* __restrict__ sorted,
                                                      const int* __restrict__ starts,
                                                      const int* __restrict__ cnt,
                                                      float* __restrict__ feat) {
    __shared__ int sidx[512];
    __shared__ f32x4 rs[256];
    __shared__ f32x4 rm[256];
    int s = blockIdx.x;
    int start = starts[s];
    int n = cnt[s];
    int t = threadIdx.x;
    int g = t >> 6;
    int l = t & 63;
    f32x4 as = (f32x4)(0.f);
    f32x4 am = (f32x4)(-INFINITY);

    for (int base = 0; base < n; base += 512) {
        int lim = n - base;
        if (lim > 512) lim = 512;
        if (t < lim) sidx[t] = sorted[start + base + t];
        if (t + 256 < lim) sidx[t + 256] = sorted[start + base + t + 256];
        __syncthreads();
        int r = g;
        for (; r + 28 < lim; r += 32) {
            int i0 = sidx[r];
            int i1 = sidx[r + 4];
            int i2 = sidx[r + 8];
            int i3 = sidx[r + 12];
            int i4 = sidx[r + 16];
            int i5 = sidx[r + 20];
            int i6 = sidx[r + 24];
            int i7 = sidx[r + 28];
            f32x4 v0 = __builtin_nontemporal_load(&x4[(size_t)i0 * 64 + l]);
            f32x4 v1 = __builtin_nontemporal_load(&x4[(size_t)i1 * 64 + l]);
            f32x4 v2 = __builtin_nontemporal_load(&x4[(size_t)i2 * 64 + l]);
            f32x4 v3 = __builtin_nontemporal_load(&x4[(size_t)i3 * 64 + l]);
            f32x4 v4 = __builtin_nontemporal_load(&x4[(size_t)i4 * 64 + l]);
            f32x4 v5 = __builtin_nontemporal_load(&x4[(size_t)i5 * 64 + l]);
            f32x4 v6 = __builtin_nontemporal_load(&x4[(size_t)i6 * 64 + l]);
            f32x4 v7 = __builtin_nontemporal_load(&x4[(size_t)i7 * 64 + l]);
            as += v0; am = __builtin_elementwise_max(am, v0);
            as += v1; am = __builtin_elementwise_max(am, v1);
            as += v2; am = __builtin_elementwise_max(am, v2);
            as += v3; am = __builtin_elementwise_max(am, v3);
            as += v4; am = __builtin_elementwise_max(am, v4);
            as += v5; am = __builtin_elementwise_max(am, v5);
            as += v6; am = __builtin_elementwise_max(am, v6);
            as += v7; am = __builtin_elementwise_max(am, v7);
        }
        for (; r < lim; r += 4) {
            int i0 = sidx[r];
            f32x4 v0 = __builtin_nontemporal_load(&x4[(size_t)i0 * 64 + l]);
            as += v0;
            am = __builtin_elementwise_max(am, v0);
        }
        __syncthreads();
    }
    rs[t] = as;
    rm[t] = am;
    __syncthreads();
    if (t < 64) {
#pragma unroll
        for (int j = 1; j < 4; ++j) {
            as += rs[t + 64 * j];
            am = __builtin_elementwise_max(am, rm[t + 64 * j]);
        }
        float inv = 1.0f / (float)(n > 0 ? n : 1);
        f32x4 mean = as * inv;
        if (n == 0) am = (f32x4)(0.f);
        f32x4* fm = (f32x4*)(feat + (size_t)s * TWOH);
        __builtin_nontemporal_store(mean, &fm[l]);
        __builtin_nontemporal_store(am, &fm[64 + l]);
    }
}

// func[f,b,h] = relu(sum_k feat[f*B+b][k] * Wf[h][k] + bf[h])
__global__ __launch_bounds__(256) void funcpool_k(const float* __restrict__ feat,
                                                  const float4* __restrict__ Wf4,
                                                  const float* __restrict__ bfv,
                                                  float* __restrict__ func) {
    __shared__ float fl[BSZ][TWOH];
    int f = blockIdx.x;
    int t = threadIdx.x;
    const float4* src = (const float4*)(feat + (size_t)f * BSZ * TWOH);
    float4* dst = (float4*)&fl[0][0];
    for (int j = t; j < BSZ * TWOH / 4; j += 256) dst[j] = src[j];
    __syncthreads();
    float acc[BSZ];
#pragma unroll
    for (int b = 0; b < BSZ; ++b) acc[b] = 0.f;
    const float4* wrow = Wf4 + (size_t)t * (TWOH / 4);
    for (int k4 = 0; k4 < TWOH / 4; ++k4) {
        float4 w = wrow[k4];
        int k = k4 * 4;
#pragma unroll
        for (int b = 0; b < BSZ; ++b) {
            acc[b] += w.x * fl[b][k] + w.y * fl[b][k + 1] + w.z * fl[b][k + 2] + w.w * fl[b][k + 3];
        }
    }
    float bias = bfv[t];
#pragma unroll
    for (int b = 0; b < BSZ; ++b) {
        float v = acc[b] + bias;
        func[((size_t)f * BSZ + b) * HDIM + t] = v > 0.f ? v : 0.f;
    }
}

// Fused: file_feat[b] = [mean_f func, max_f func] then out[b]=relu(file_feat@Wg^T+bg).
__global__ __launch_bounds__(256) void filefinal_k(const float* __restrict__ func,
                                                   const float4* __restrict__ Wg4,
                                                   const float* __restrict__ bg,
                                                   float* __restrict__ out) {
    __shared__ float fl[TWOH];
    int b = blockIdx.x;
    int t = threadIdx.x;
    float s = 0.f, m = -INFINITY;
#pragma unroll 4
    for (int f = 0; f < FNUM; ++f) {
        float v = func[((size_t)f * BSZ + b) * HDIM + t];
        s += v;
        m = fmaxf(m, v);
    }
    fl[t] = s * (1.0f / FNUM);
    fl[HDIM + t] = m;
    __syncthreads();
    float acc = 0.f;
    const float4* wr = Wg4 + (size_t)t * (TWOH / 4);
    for (int k4 = 0; k4 < TWOH / 4; ++k4) {
        float4 w = wr[k4];
        int k = k4 * 4;
        acc += w.x * fl[k] + w.y * fl[k + 1] + w.z * fl[k + 2] + w.w * fl[k + 3];
    }
    float v = acc + bg[t];
    out[b * HDIM + t] = v > 0.f ? v : 0.f;
}

extern "C" void kernel_launch(void* const* d_in, const int* in_sizes, int n_in,
                              void* d_out, int out_size, void* d_ws, size_t ws_size,
                              hipStream_t stream) {
    const float* x = (const float*)d_in[0];
    const int* batch = (const int*)d_in[1];
    const int* fid = (const int*)d_in[2];
    const float* Wf = (const float*)d_in[3];
    const float* bfv = (const float*)d_in[4];
    const float* Wg = (const float*)d_in[5];
    const float* bg = (const float*)d_in[6];
    float* out = (float*)d_out;
    int N = in_sizes[1];

    int* sorted = (int*)d_ws;                                   // N ints
    int* hist_t = sorted + N;                                   // SEGS*NBLK ints (2 MB)
    int* starts = hist_t + (size_t)SEGS * NBLK;                 // SEGS
    int* cnt = starts + SEGS;                                   // SEGS
    float* feat = (float*)(cnt + SEGS);                         // SEGS*TWOH
    float* func = feat + (size_t)SEGS * TWOH;                   // SEGS*HDIM
    unsigned short* seg16 = (unsigned short*)(func + (size_t)SEGS * HDIM);  // N u16

    int chunk = ((N + NBLK - 1) / NBLK + 3) & ~3;  // multiple of 4 for int4 paths

    hist_k<<<NBLK, 256, 0, stream>>>(batch, fid, seg16, hist_t, N, chunk);
    segscan_k<<<SEGS / 4, 256, 0, stream>>>(hist_t, cnt);
    scan_k<<<1, 256, 0, stream>>>(cnt, starts);
    scatter_k<<<NBLK, 256, 0, stream>>>(seg16, hist_t, starts, sorted, N, chunk);
    segreduce_k<<<SEGS, 256, 0, stream>>>((const f32x4*)x, sorted, starts, cnt, feat);
    funcpool_k<<<FNUM, 256, 0, stream>>>(feat, (const float4*)Wf, bfv, func);
    filefinal_k<<<BSZ, 256, 0, stream>>>(func, (const float4*)Wg, bg, out);
}

// Round 7
// 260.666 us; speedup vs baseline: 1.0018x; 1.0018x over previous
//
#include <hip/hip_runtime.h>
#include <math.h>

#define HDIM 256
#define BSZ 8
#define FNUM 256
#define SEGS (FNUM * BSZ)   /* 2048 */
#define TWOH 512
#define NBLK 256            /* blocks in hist/scatter phases */

typedef float f32x4 __attribute__((ext_vector_type(4)));

// Phase 1: per-block LDS histogram + cache seg ids as u16. 1024 threads for occupancy.
__global__ __launch_bounds__(1024) void hist_k(const int* __restrict__ batch,
                                               const int* __restrict__ fid,
                                               unsigned short* __restrict__ seg16,
                                               int* __restrict__ hist_t,
                                               int N, int chunk) {
    __shared__ int h[SEGS];
    int p = blockIdx.x, t = threadIdx.x;
    for (int s = t; s < SEGS; s += 1024) h[s] = 0;
    __syncthreads();
    int beg = p * chunk;
    int end = beg + chunk; if (end > N) end = N;
    if (beg < end) {
        int nv = (end - beg) >> 2;
        const int4* b4 = (const int4*)(batch + beg);
        const int4* f4 = (const int4*)(fid + beg);
        ushort4* s4 = (ushort4*)(seg16 + beg);
        for (int j = t; j < nv; j += 1024) {
            int4 bb = b4[j];
            int4 ff = f4[j];
            int s0 = ff.x * BSZ + bb.x;
            int s1 = ff.y * BSZ + bb.y;
            int s2 = ff.z * BSZ + bb.z;
            int s3 = ff.w * BSZ + bb.w;
            s4[j] = make_ushort4((unsigned short)s0, (unsigned short)s1,
                                 (unsigned short)s2, (unsigned short)s3);
            atomicAdd(&h[s0], 1);
            atomicAdd(&h[s1], 1);
            atomicAdd(&h[s2], 1);
            atomicAdd(&h[s3], 1);
        }
        for (int i = beg + (nv << 2) + t; i < end; i += 1024) {
            int s = fid[i] * BSZ + batch[i];
            seg16[i] = (unsigned short)s;
            atomicAdd(&h[s], 1);
        }
    }
    __syncthreads();
    for (int s = t; s < SEGS; s += 1024)
        hist_t[(size_t)s * NBLK + p] = h[s];
}

// Phase 2a: one WAVE per segment; lane l owns 4 contiguous block-counts (int4).
__global__ __launch_bounds__(256) void segscan_k(int* __restrict__ hist_t,
                                                 int* __restrict__ cnt) {
    int wid = (int)((blockIdx.x * 256 + threadIdx.x) >> 6);  // segment id
    int lane = threadIdx.x & 63;
    if (wid >= SEGS) return;
    int4* row = (int4*)(hist_t + (size_t)wid * NBLK) + lane;
    int4 a = *row;
    int lsum = a.x + a.y + a.z + a.w;
    int inc = lsum;
#pragma unroll
    for (int off = 1; off < 64; off <<= 1) {
        int v = __shfl_up(inc, off, 64);
        if (lane >= off) inc += v;
    }
    int r = inc - lsum;  // exclusive base for this lane
    int4 oa;
    oa.x = r; r += a.x; oa.y = r; r += a.y; oa.z = r; r += a.z; oa.w = r; r += a.w;
    *row = oa;
    if (lane == 63) cnt[wid] = inc;
}

// Phase 2b: exclusive scan of 2048 totals -> segment starts. One block.
__global__ void scan_k(const int* __restrict__ cnt, int* __restrict__ starts) {
    __shared__ int part[256];
    int t = threadIdx.x;
    int local[8];
    int s = 0;
#pragma unroll
    for (int j = 0; j < 8; ++j) { local[j] = cnt[t * 8 + j]; s += local[j]; }
    part[t] = s;
    __syncthreads();
    for (int off = 1; off < 256; off <<= 1) {
        int v = (t >= off) ? part[t - off] : 0;
        __syncthreads();
        part[t] += v;
        __syncthreads();
    }
    int run = (t == 0) ? 0 : part[t - 1];
#pragma unroll
    for (int j = 0; j < 8; ++j) {
        starts[t * 8 + j] = run;
        run += local[j];
    }
}

// Phase 3: deterministic-base scatter; LDS atomics only. 1024 threads for occupancy.
__global__ __launch_bounds__(1024) void scatter_k(const unsigned short* __restrict__ seg16,
                                                  const int* __restrict__ hist_t,
                                                  const int* __restrict__ starts,
                                                  int* __restrict__ sorted,
                                                  int N, int chunk) {
    __shared__ int off[SEGS];
    int p = blockIdx.x, t = threadIdx.x;
    for (int s = t; s < SEGS; s += 1024)
        off[s] = starts[s] + hist_t[(size_t)s * NBLK + p];
    __syncthreads();
    int beg = p * chunk;
    int end = beg + chunk; if (end > N) end = N;
    if (beg < end) {
        int nv = (end - beg) >> 2;
        const ushort4* s4 = (const ushort4*)(seg16 + beg);
        for (int j = t; j < nv; j += 1024) {
            ushort4 ss = s4[j];
            int i0 = beg + 4 * j;
            sorted[atomicAdd(&off[ss.x], 1)] = i0;
            sorted[atomicAdd(&off[ss.y], 1)] = i0 + 1;
            sorted[atomicAdd(&off[ss.z], 1)] = i0 + 2;
            sorted[atomicAdd(&off[ss.w], 1)] = i0 + 3;
        }
        for (int i = beg + (nv << 2) + t; i < end; i += 1024)
            sorted[atomicAdd(&off[seg16[i]], 1)] = i;
    }
}

// one block per segment: 256 threads = 64 lanes (float4 over 256 dims) x 4 row groups.
// 8-deep row unroll: 8 outstanding 1 KB wave-gathers; 512-row index chunks.
__global__ __launch_bounds__(256, 8) void segreduce_k(const f32x4* __restrict__ x4,
                                                      const int* __restrict__ sorted,
                                                      const int* __restrict__ starts,
                                                      const int* __restrict__ cnt,
                                                      float* __restrict__ feat) {
    __shared__ int sidx[512];
    __shared__ f32x4 rs[256];
    __shared__ f32x4 rm[256];
    int s = blockIdx.x;
    int start = starts[s];
    int n = cnt[s];
    int t = threadIdx.x;
    int g = t >> 6;
    int l = t & 63;
    f32x4 as = (f32x4)(0.f);
    f32x4 am = (f32x4)(-INFINITY);

    for (int base = 0; base < n; base += 512) {
        int lim = n - base;
        if (lim > 512) lim = 512;
        if (t < lim) sidx[t] = sorted[start + base + t];
        if (t + 256 < lim) sidx[t + 256] = sorted[start + base + t + 256];
        __syncthreads();
        int r = g;
        for (; r + 28 < lim; r += 32) {
            int i0 = sidx[r];
            int i1 = sidx[r + 4];
            int i2 = sidx[r + 8];
            int i3 = sidx[r + 12];
            int i4 = sidx[r + 16];
            int i5 = sidx[r + 20];
            int i6 = sidx[r + 24];
            int i7 = sidx[r + 28];
            f32x4 v0 = __builtin_nontemporal_load(&x4[(size_t)i0 * 64 + l]);
            f32x4 v1 = __builtin_nontemporal_load(&x4[(size_t)i1 * 64 + l]);
            f32x4 v2 = __builtin_nontemporal_load(&x4[(size_t)i2 * 64 + l]);
            f32x4 v3 = __builtin_nontemporal_load(&x4[(size_t)i3 * 64 + l]);
            f32x4 v4 = __builtin_nontemporal_load(&x4[(size_t)i4 * 64 + l]);
            f32x4 v5 = __builtin_nontemporal_load(&x4[(size_t)i5 * 64 + l]);
            f32x4 v6 = __builtin_nontemporal_load(&x4[(size_t)i6 * 64 + l]);
            f32x4 v7 = __builtin_nontemporal_load(&x4[(size_t)i7 * 64 + l]);
            as += v0; am = __builtin_elementwise_max(am, v0);
            as += v1; am = __builtin_elementwise_max(am, v1);
            as += v2; am = __builtin_elementwise_max(am, v2);
            as += v3; am = __builtin_elementwise_max(am, v3);
            as += v4; am = __builtin_elementwise_max(am, v4);
            as += v5; am = __builtin_elementwise_max(am, v5);
            as += v6; am = __builtin_elementwise_max(am, v6);
            as += v7; am = __builtin_elementwise_max(am, v7);
        }
        for (; r < lim; r += 4) {
            int i0 = sidx[r];
            f32x4 v0 = __builtin_nontemporal_load(&x4[(size_t)i0 * 64 + l]);
            as += v0;
            am = __builtin_elementwise_max(am, v0);
        }
        __syncthreads();
    }
    rs[t] = as;
    rm[t] = am;
    __syncthreads();
    if (t < 64) {
#pragma unroll
        for (int j = 1; j < 4; ++j) {
            as += rs[t + 64 * j];
            am = __builtin_elementwise_max(am, rm[t + 64 * j]);
        }
        float inv = 1.0f / (float)(n > 0 ? n : 1);
        f32x4 mean = as * inv;
        if (n == 0) am = (f32x4)(0.f);
        f32x4* fm = (f32x4*)(feat + (size_t)s * TWOH);
        __builtin_nontemporal_store(mean, &fm[l]);
        __builtin_nontemporal_store(am, &fm[64 + l]);
    }
}

// func[f,b,h] = relu(sum_k feat[f*B+b][k] * Wf[h][k] + bf[h])
__global__ __launch_bounds__(256) void funcpool_k(const float* __restrict__ feat,
                                                  const float4* __restrict__ Wf4,
                                                  const float* __restrict__ bfv,
                                                  float* __restrict__ func) {
    __shared__ float fl[BSZ][TWOH];
    int f = blockIdx.x;
    int t = threadIdx.x;
    const float4* src = (const float4*)(feat + (size_t)f * BSZ * TWOH);
    float4* dst = (float4*)&fl[0][0];
    for (int j = t; j < BSZ * TWOH / 4; j += 256) dst[j] = src[j];
    __syncthreads();
    float acc[BSZ];
#pragma unroll
    for (int b = 0; b < BSZ; ++b) acc[b] = 0.f;
    const float4* wrow = Wf4 + (size_t)t * (TWOH / 4);
    for (int k4 = 0; k4 < TWOH / 4; ++k4) {
        float4 w = wrow[k4];
        int k = k4 * 4;
#pragma unroll
        for (int b = 0; b < BSZ; ++b) {
            acc[b] += w.x * fl[b][k] + w.y * fl[b][k + 1] + w.z * fl[b][k + 2] + w.w * fl[b][k + 3];
        }
    }
    float bias = bfv[t];
#pragma unroll
    for (int b = 0; b < BSZ; ++b) {
        float v = acc[b] + bias;
        func[((size_t)f * BSZ + b) * HDIM + t] = v > 0.f ? v : 0.f;
    }
}

// Fused: file_feat[b] = [mean_f func, max_f func] then out[b]=relu(file_feat@Wg^T+bg).
__global__ __launch_bounds__(256) void filefinal_k(const float* __restrict__ func,
                                                   const float4* __restrict__ Wg4,
                                                   const float* __restrict__ bg,
                                                   float* __restrict__ out) {
    __shared__ float fl[TWOH];
    int b = blockIdx.x;
    int t = threadIdx.x;
    float s = 0.f, m = -INFINITY;
#pragma unroll 4
    for (int f = 0; f < FNUM; ++f) {
        float v = func[((size_t)f * BSZ + b) * HDIM + t];
        s += v;
        m = fmaxf(m, v);
    }
    fl[t] = s * (1.0f / FNUM);
    fl[HDIM + t] = m;
    __syncthreads();
    float acc = 0.f;
    const float4* wr = Wg4 + (size_t)t * (TWOH / 4);
    for (int k4 = 0; k4 < TWOH / 4; ++k4) {
        float4 w = wr[k4];
        int k = k4 * 4;
        acc += w.x * fl[k] + w.y * fl[k + 1] + w.z * fl[k + 2] + w.w * fl[k + 3];
    }
    float v = acc + bg[t];
    out[b * HDIM + t] = v > 0.f ? v : 0.f;
}

extern "C" void kernel_launch(void* const* d_in, const int* in_sizes, int n_in,
                              void* d_out, int out_size, void* d_ws, size_t ws_size,
                              hipStream_t stream) {
    const float* x = (const float*)d_in[0];
    const int* batch = (const int*)d_in[1];
    const int* fid = (const int*)d_in[2];
    const float* Wf = (const float*)d_in[3];
    const float* bfv = (const float*)d_in[4];
    const float* Wg = (const float*)d_in[5];
    const float* bg = (const float*)d_in[6];
    float* out = (float*)d_out;
    int N = in_sizes[1];

    int* sorted = (int*)d_ws;                                   // N ints
    int* hist_t = sorted + N;                                   // SEGS*NBLK ints (2 MB)
    int* starts = hist_t + (size_t)SEGS * NBLK;                 // SEGS
    int* cnt = starts + SEGS;                                   // SEGS
    float* feat = (float*)(cnt + SEGS);                         // SEGS*TWOH
    float* func = feat + (size_t)SEGS * TWOH;                   // SEGS*HDIM
    unsigned short* seg16 = (unsigned short*)(func + (size_t)SEGS * HDIM);  // N u16

    int chunk = ((N + NBLK - 1) / NBLK + 3) & ~3;  // multiple of 4 for int4 paths

    hist_k<<<NBLK, 1024, 0, stream>>>(batch, fid, seg16, hist_t, N, chunk);
    segscan_k<<<SEGS / 4, 256, 0, stream>>>(hist_t, cnt);
    scan_k<<<1, 256, 0, stream>>>(cnt, starts);
    scatter_k<<<NBLK, 1024, 0, stream>>>(seg16, hist_t, starts, sorted, N, chunk);
    segreduce_k<<<SEGS, 256, 0, stream>>>((const f32x4*)x, sorted, starts, cnt, feat);
    funcpool_k<<<FNUM, 256, 0, stream>>>(feat, (const float4*)Wf, bfv, func);
    filefinal_k<<<BSZ, 256, 0, stream>>>(func, (const float4*)Wg, bg, out);
}